// Round 3
// baseline (1715.826 us; speedup 1.0000x reference)
//
#include <hip/hip_runtime.h>
#include <hip/hip_bf16.h>

static constexpr int Bn = 32;
static constexpr int Hin = 256, Win = 256;
static constexpr int C1 = 64, H1 = 128, W1 = 128;
static constexpr int C2 = 32, H2 = 64, W2 = 64;
static constexpr int Dd = 64;    // latent dim
static constexpr int Kc = 512;   // codebook entries
static constexpr int ROWS = Bn * H2 * W2;  // 131072

// ws layout (floats): lossA(64) | idx(131072 ints) | chunk buffers
static constexpr int FIX_FLOATS = 64 + ROWS;     // 131,136
static constexpr int H1_PER_N = C1 * H1 * W1;    // 1,048,576
static constexpr int Z_PER_N  = H2 * W2 * Dd;    // 262,144
static constexpr int H2_PER_N = C2 * H2 * W2;    // 131,072

__global__ void k_zero(float* p) { p[threadIdx.x] = 0.f; }

// ---------- enc conv1: 3->64, 3x3, s2, p1, ReLU ----------
// grid: ((n*4 + cc)*16 + yt)*2 + xt ; n = chunk-local
__global__ __launch_bounds__(256) void k_conv1(
    const float* __restrict__ x, const float* __restrict__ w,
    const float* __restrict__ b, float* __restrict__ h1, int n0)
{
  int bid = blockIdx.x;
  int xt = bid & 1, yt = (bid >> 1) & 15, cc = (bid >> 5) & 3, n = bid >> 7;
  int X0 = xt * 64, Y0 = yt * 8, co0 = cc * 16;
  __shared__ float sIn[3][17][130];
  int tid = threadIdx.x;
  for (int i = tid; i < 3 * 17 * 130; i += 256) {
    int ci = i / (17 * 130);
    int rr = (i / 130) % 17;
    int ccx = i % 130;
    int gy = 2 * Y0 - 1 + rr, gx = 2 * X0 - 1 + ccx;
    float v = 0.f;
    if (gy >= 0 && gy < Hin && gx >= 0 && gx < Win)
      v = x[(((size_t)(n0 + n) * 3 + ci) * Hin + gy) * Win + gx];
    sIn[ci][rr][ccx] = v;
  }
  __syncthreads();
  int lx = tid & 63, ys = tid >> 6;
  float acc[16][2];
#pragma unroll
  for (int c = 0; c < 16; ++c) { acc[c][0] = 0.f; acc[c][1] = 0.f; }
#pragma unroll
  for (int ci = 0; ci < 3; ++ci)
#pragma unroll
    for (int ky = 0; ky < 3; ++ky)
#pragma unroll
      for (int kx = 0; kx < 3; ++kx) {
        float u0 = sIn[ci][2 * ys + ky][2 * lx + kx];
        float u1 = sIn[ci][2 * ys + 8 + ky][2 * lx + kx];
#pragma unroll
        for (int c = 0; c < 16; ++c) {
          float wv = w[((co0 + c) * 3 + ci) * 9 + ky * 3 + kx];
          acc[c][0] += u0 * wv;
          acc[c][1] += u1 * wv;
        }
      }
#pragma unroll
  for (int c = 0; c < 16; ++c) {
    float bv = b[co0 + c];
    float v0 = acc[c][0] + bv; v0 = v0 > 0.f ? v0 : 0.f;
    float v1 = acc[c][1] + bv; v1 = v1 > 0.f ? v1 : 0.f;
    h1[((n * C1 + co0 + c) * H1 + Y0 + ys) * W1 + X0 + lx] = v0;
    h1[((n * C1 + co0 + c) * H1 + Y0 + ys + 4) * W1 + X0 + lx] = v1;
  }
}

// ---------- enc conv2: 64->32, 3x3, s2, p1, ReLU ----------
// grid: (n*2 + cc)*8 + yt ; chunk-local
__global__ __launch_bounds__(256) void k_conv2(
    const float* __restrict__ h1, const float* __restrict__ w,
    const float* __restrict__ b, float* __restrict__ h2)
{
  int bid = blockIdx.x;
  int yt = bid & 7, cc = (bid >> 3) & 1, n = bid >> 4;
  int Y0 = yt * 8, co0 = cc * 16;
  __shared__ float sIn[4][17][130];
  int tid = threadIdx.x;
  int lx = tid & 63, ys = tid >> 6;
  float acc[16][2];
#pragma unroll
  for (int c = 0; c < 16; ++c) { acc[c][0] = 0.f; acc[c][1] = 0.f; }
  for (int cb0 = 0; cb0 < C1; cb0 += 4) {
    __syncthreads();
    for (int i = tid; i < 4 * 17 * 130; i += 256) {
      int ci = i / (17 * 130);
      int rr = (i / 130) % 17;
      int ccx = i % 130;
      int gy = 2 * Y0 - 1 + rr, gx = -1 + ccx;
      float v = 0.f;
      if (gy >= 0 && gy < H1 && gx >= 0 && gx < W1)
        v = h1[((n * C1 + cb0 + ci) * H1 + gy) * W1 + gx];
      sIn[ci][rr][ccx] = v;
    }
    __syncthreads();
#pragma unroll
    for (int ci = 0; ci < 4; ++ci)
#pragma unroll
      for (int ky = 0; ky < 3; ++ky)
#pragma unroll
        for (int kx = 0; kx < 3; ++kx) {
          float u0 = sIn[ci][2 * ys + ky][2 * lx + kx];
          float u1 = sIn[ci][2 * ys + 8 + ky][2 * lx + kx];
#pragma unroll
          for (int c = 0; c < 16; ++c) {
            float wv = w[((co0 + c) * C1 + cb0 + ci) * 9 + ky * 3 + kx];
            acc[c][0] += u0 * wv;
            acc[c][1] += u1 * wv;
          }
        }
  }
#pragma unroll
  for (int c = 0; c < 16; ++c) {
    float bv = b[co0 + c];
    float v0 = acc[c][0] + bv; v0 = v0 > 0.f ? v0 : 0.f;
    float v1 = acc[c][1] + bv; v1 = v1 > 0.f ? v1 : 0.f;
    h2[((n * C2 + co0 + c) * H2 + Y0 + ys) * W2 + lx] = v0;
    h2[((n * C2 + co0 + c) * H2 + Y0 + ys + 4) * W2 + lx] = v1;
  }
}

// ---------- enc conv3 (1x1, 32->64) -> z in [row][64] (chunk-local rows) ----------
__global__ __launch_bounds__(256) void k_conv3z(
    const float* __restrict__ h2, const float* __restrict__ w,
    const float* __restrict__ b, float* __restrict__ z)
{
  int bid = blockIdx.x;
  int y = bid & 63, n = bid >> 6;
  __shared__ float sH[C2][64];
  __shared__ float sW[Dd * 33];
  int tid = threadIdx.x;
  for (int i = tid; i < C2 * 64; i += 256) {
    int ci = i >> 6, xx = i & 63;
    sH[ci][xx] = h2[((n * C2 + ci) * H2 + y) * W2 + xx];
  }
  for (int i = tid; i < Dd * C2; i += 256) {
    int d = i >> 5, ci = i & 31;
    sW[d * 33 + ci] = w[i];
  }
  __syncthreads();
  int dg = tid & 3, lx = tid >> 2;
  float acc[16];
#pragma unroll
  for (int j = 0; j < 16; ++j) acc[j] = 0.f;
  for (int ci = 0; ci < C2; ++ci) {
    float u = sH[ci][lx];
#pragma unroll
    for (int j = 0; j < 16; ++j)
      acc[j] += u * sW[(dg * 16 + j) * 33 + ci];
  }
  int row = (n * H2 + y) * W2 + lx;
#pragma unroll
  for (int j = 0; j < 16; ++j)
    z[row * Dd + dg * 16 + j] = acc[j] + b[dg * 16 + j];
}

// ---------- VQ: argmin + loss; z chunk-local, idx global ----------
__global__ __launch_bounds__(256) void k_vq(
    const float* __restrict__ z, const float* __restrict__ cbf,
    int* __restrict__ idx, float* __restrict__ lossA, int row0)
{
  __shared__ float c2s[Kc];
  int tid = threadIdx.x;
  for (int c = tid; c < Kc; c += 256) {
    float s = 0.f;
#pragma unroll
    for (int d = 0; d < Dd; ++d) { float v = cbf[c * Dd + d]; s += v * v; }
    c2s[c] = s;
  }
  __syncthreads();
  int r = blockIdx.x * 256 + tid;
  float4 zr[16];
  const float4* zp = (const float4*)(z + (size_t)r * Dd);
#pragma unroll
  for (int i = 0; i < 16; ++i) zr[i] = zp[i];
  float best = 1e30f; int bidx = 0;
  for (int c = 0; c < Kc; ++c) {
    const float* __restrict__ cr = cbf + c * Dd;
    float d0 = 0.f, d1 = 0.f, d2a = 0.f, d3 = 0.f;
#pragma unroll
    for (int i = 0; i < 16; ++i) {
      d0 += zr[i].x * cr[4 * i + 0];
      d1 += zr[i].y * cr[4 * i + 1];
      d2a += zr[i].z * cr[4 * i + 2];
      d3 += zr[i].w * cr[4 * i + 3];
    }
    float dot = (d0 + d1) + (d2a + d3);
    float dist = c2s[c] - 2.f * dot;
    if (dist < best) { best = dist; bidx = c; }
  }
  idx[row0 + r] = bidx;
  const float* cr = cbf + bidx * Dd;
  float ls = 0.f;
#pragma unroll
  for (int i = 0; i < 16; ++i) {
    float e0 = zr[i].x - cr[4 * i + 0];
    float e1 = zr[i].y - cr[4 * i + 1];
    float e2 = zr[i].z - cr[4 * i + 2];
    float e3 = zr[i].w - cr[4 * i + 3];
    ls += e0 * e0 + e1 * e1 + e2 * e2 + e3 * e3;
  }
#pragma unroll
  for (int off = 32; off > 0; off >>= 1) ls += __shfl_down(ls, off);
  if ((tid & 63) == 0) atomicAdd(lossA, ls);
}

__global__ void k_loss_final(const float* __restrict__ a, float* __restrict__ out)
{
  if (threadIdx.x == 0) {
    float l = a[0] / (float)(ROWS * Dd);   // / 2^23, exact
    out[0] = l;
    out[1] = l;
  }
}

// ---------- dec conv1 (1x1, 64->32, ReLU); idx global, d1 chunk-local ----------
__global__ __launch_bounds__(256) void k_dec1(
    const int* __restrict__ idx, const float* __restrict__ cbf,
    const float* __restrict__ w, const float* __restrict__ b,
    float* __restrict__ d1, int row0)
{
  int bid = blockIdx.x;
  int y = bid & 63, n = bid >> 6;
  __shared__ float sZ[64 * 65];
  __shared__ float sW[32 * 65];
  int tid = threadIdx.x;
  int base = row0 + (n * H2 + y) * W2;
  {
    int d = tid & 63, x0 = tid >> 6;
    for (int k = 0; k < 16; ++k) {
      int xx = x0 + 4 * k;
      int ci = idx[base + xx];
      sZ[xx * 65 + d] = cbf[ci * Dd + d];
    }
  }
  for (int i = tid; i < 32 * Dd; i += 256) {
    int co = i >> 6, d = i & 63;
    sW[co * 65 + d] = w[i];
  }
  __syncthreads();
  int lx = tid & 63, cg = tid >> 6;
  float acc[8];
#pragma unroll
  for (int j = 0; j < 8; ++j) acc[j] = 0.f;
  for (int d = 0; d < Dd; ++d) {
    float u = sZ[lx * 65 + d];
#pragma unroll
    for (int j = 0; j < 8; ++j)
      acc[j] += u * sW[(cg * 8 + j) * 65 + d];
  }
#pragma unroll
  for (int j = 0; j < 8; ++j) {
    int co = cg * 8 + j;
    float v = acc[j] + b[co];
    v = v > 0.f ? v : 0.f;
    d1[((n * C2 + co) * H2 + y) * W2 + lx] = v;
  }
}

// ---------- fused bilinear upsample2x + 3x3 conv (pad 1) ----------
// jax.image.resize bilinear: u even: k={u/2-1,u/2} w={.25,.75}; u odd: k={u/2,u/2+1}
// w={.75,.25}; k edge-clamped. Conv pad: U outside [0,2Hi) is ZERO.
template <int Ci, int Hi, int Co, int COCH, bool RELU>
__global__ __launch_bounds__(256) void k_upconv(
    const float* __restrict__ I, const float* __restrict__ w,
    const float* __restrict__ bias, float* __restrict__ O, int n0)
{
  constexpr int Wi = Hi, Ho = 2 * Hi, Wo = 2 * Hi;
  constexpr int TW = Ho / 32;
  constexpr int NCG = Co / COCH;
  int bid = blockIdx.x;
  int tx = bid % TW; bid /= TW;
  int ty = bid % TW; bid /= TW;
  int cg = bid % NCG; bid /= NCG;
  int n = bid;  // chunk-local
  int Y0 = ty * 32, X0 = tx * 32;
  int kyb = Y0 / 2 - 1, kxb = X0 / 2 - 1;

  __shared__ float sI[2][18 * 19];
  __shared__ float sU[2][34 * 35];

  int tid = threadIdx.x;
  int lx = tid & 31, yg = tid >> 5;
  int yb = yg * 4;

  float acc[COCH][4];
#pragma unroll
  for (int j = 0; j < COCH; ++j)
#pragma unroll
    for (int yy = 0; yy < 4; ++yy) acc[j][yy] = 0.f;

  for (int c0 = 0; c0 < Ci; c0 += 2) {
    __syncthreads();
    for (int i = tid; i < 2 * 18 * 18; i += 256) {
      int s = i / 324, r2 = i % 324;
      int rr = r2 / 18, cc = r2 % 18;
      int gy = kyb + rr; gy = gy < 0 ? 0 : (gy > Hi - 1 ? Hi - 1 : gy);
      int gx = kxb + cc; gx = gx < 0 ? 0 : (gx > Wi - 1 ? Wi - 1 : gx);
      sI[s][rr * 19 + cc] = I[((n * Ci + c0 + s) * Hi + gy) * Wi + gx];
    }
    __syncthreads();
    for (int i = tid; i < 2 * 34 * 34; i += 256) {
      int s = i / 1156, r2 = i % 1156;
      int iy = r2 / 34, ix = r2 % 34;
      int uy = Y0 - 1 + iy, ux = X0 - 1 + ix;
      float v = 0.f;
      if (uy >= 0 && uy < Ho && ux >= 0 && ux < Wo) {
        int ky0, ky1, kx0, kx1;
        float ay0, ax0;
        if (uy & 1) { ky0 = uy >> 1; ky1 = ky0 + 1; ay0 = 0.75f; }
        else        { ky1 = uy >> 1; ky0 = ky1 - 1; ay0 = 0.25f; }
        if (ux & 1) { kx0 = ux >> 1; kx1 = kx0 + 1; ax0 = 0.75f; }
        else        { kx1 = ux >> 1; kx0 = kx1 - 1; ax0 = 0.25f; }
        ky0 = (ky0 < 0 ? 0 : (ky0 > Hi - 1 ? Hi - 1 : ky0)) - kyb;
        ky1 = (ky1 < 0 ? 0 : (ky1 > Hi - 1 ? Hi - 1 : ky1)) - kyb;
        kx0 = (kx0 < 0 ? 0 : (kx0 > Wi - 1 ? Wi - 1 : kx0)) - kxb;
        kx1 = (kx1 < 0 ? 0 : (kx1 > Wi - 1 ? Wi - 1 : kx1)) - kxb;
        float ay1 = 1.f - ay0, ax1 = 1.f - ax0;
        float v00 = sI[s][ky0 * 19 + kx0], v01 = sI[s][ky0 * 19 + kx1];
        float v10 = sI[s][ky1 * 19 + kx0], v11 = sI[s][ky1 * 19 + kx1];
        v = ay0 * (ax0 * v00 + ax1 * v01) + ay1 * (ax0 * v10 + ax1 * v11);
      }
      sU[s][iy * 35 + ix] = v;
    }
    __syncthreads();
#pragma unroll
    for (int s = 0; s < 2; ++s) {
      float u[6][3];
#pragma unroll
      for (int rr = 0; rr < 6; ++rr)
#pragma unroll
        for (int cc = 0; cc < 3; ++cc)
          u[rr][cc] = sU[s][(yb + rr) * 35 + lx + cc];
      int ci = c0 + s;
#pragma unroll
      for (int j = 0; j < COCH; ++j) {
        const float* wp = w + ((cg * COCH + j) * Ci + ci) * 9;
#pragma unroll
        for (int ky = 0; ky < 3; ++ky)
#pragma unroll
          for (int kx = 0; kx < 3; ++kx) {
            float wv = wp[ky * 3 + kx];
#pragma unroll
            for (int yy = 0; yy < 4; ++yy)
              acc[j][yy] += u[yy + ky][kx] * wv;
          }
      }
    }
  }
#pragma unroll
  for (int j = 0; j < COCH; ++j) {
    int co = cg * COCH + j;
    float bv = bias[co];
#pragma unroll
    for (int yy = 0; yy < 4; ++yy) {
      float v = acc[j][yy] + bv;
      if (RELU) v = v > 0.f ? v : 0.f;
      int gy = Y0 + yb + yy, gx = X0 + lx;
      size_t off = ((size_t)((n0 + n) * Co + co) * Ho + gy) * Wo + gx;
      O[off] = v;
    }
  }
}

extern "C" void kernel_launch(void* const* d_in, const int* in_sizes, int n_in,
                              void* d_out, int out_size, void* d_ws, size_t ws_size,
                              hipStream_t stream)
{
  // All inputs are float32 per the reference (setup_inputs uses jnp.float32).
  const float* x      = (const float*)d_in[0];
  const float* cb     = (const float*)d_in[1];
  const float* enc_w1 = (const float*)d_in[2];
  const float* enc_b1 = (const float*)d_in[3];
  const float* enc_w2 = (const float*)d_in[4];
  const float* enc_b2 = (const float*)d_in[5];
  const float* enc_w3 = (const float*)d_in[6];
  const float* enc_b3 = (const float*)d_in[7];
  const float* dec_w1 = (const float*)d_in[8];
  const float* dec_b1 = (const float*)d_in[9];
  const float* dec_w2 = (const float*)d_in[10];
  const float* dec_b2 = (const float*)d_in[11];
  const float* dec_w3 = (const float*)d_in[12];
  const float* dec_b3 = (const float*)d_in[13];

  float* ws = (float*)d_ws;
  float* lossA = ws;                      // 64
  int* idx = (int*)(lossA + 64);          // ROWS ints
  float* chunkbuf = (float*)(idx + ROWS);

  // pick the largest batch-chunk CH that fits ws_size
  int CH = 1;
  for (int c = 32; c >= 1; c >>= 1) {
    size_t need = ((size_t)FIX_FLOATS + (size_t)(H1_PER_N + Z_PER_N + H2_PER_N) * c) * 4;
    if (need <= ws_size) { CH = c; break; }
  }
  float* h1 = chunkbuf;                   // CH * 1,048,576  (reused as d2)
  float* z  = h1 + (size_t)H1_PER_N * CH; // CH * 262,144
  float* h2 = z + (size_t)Z_PER_N * CH;   // CH * 131,072    (reused as d1)

  k_zero<<<1, 64, 0, stream>>>(lossA);

  float* out = (float*)d_out;

  for (int n0 = 0; n0 < Bn; n0 += CH) {
    int row0 = n0 * H2 * W2;
    k_conv1<<<CH * 128, 256, 0, stream>>>(x, enc_w1, enc_b1, h1, n0);
    k_conv2<<<CH * 16, 256, 0, stream>>>(h1, enc_w2, enc_b2, h2);
    k_conv3z<<<CH * 64, 256, 0, stream>>>(h2, enc_w3, enc_b3, z);
    k_vq<<<CH * 16, 256, 0, stream>>>(z, cb, idx, lossA, row0);
    k_dec1<<<CH * 64, 256, 0, stream>>>(idx, cb, dec_w1, dec_b1, h2, row0);
    // d1 (h2 region) -> d2 (h1 region): 32ch 64x64 -> 64ch 128x128, ReLU
    k_upconv<32, 64, 64, 8, true><<<CH * 8 * 4 * 4, 256, 0, stream>>>(
        h2, dec_w2, dec_b2, h1, 0);
    // d2 -> recon: 64ch 128x128 -> 3ch 256x256, no relu, f32 out at offset 2
    k_upconv<64, 128, 3, 3, false><<<CH * 1 * 8 * 8, 256, 0, stream>>>(
        h1, dec_w3, dec_b3, out + 2, n0);
  }
  k_loss_final<<<1, 64, 0, stream>>>(lossA, out);
}